// Round 4
// baseline (16.186 us; speedup 1.0000x reference)
//
#include <hip/hip_runtime.h>

// out[b,n,k] = |scale| * sum_d (table[d,k] - x[b,n,d])^2
//            = |scale| * ( T2[k] + X2[row] - 2 * dot(x_row, t_k) )
// B=4, N=2048, D=64, K=256, fp32.
//
// R4: 8 rows/wave (halves L2 table traffic: 128MB -> 64MB ~ 1.9us @34.5TB/s),
// 4 waves/block -> 256 blocks x 256 threads (1 block/CU). Wave covers all
// 256 k via float4 table loads; x staged in LDS, broadcast ds_read_b128.

#define TD_D  64
#define TD_K  256
#define TD_RW 8          // rows per wave
#define TD_W  4          // waves per block

typedef float f4 __attribute__((ext_vector_type(4)));

__global__ __launch_bounds__(256)
void TableDistance_5669356831001_kernel(
    const float* __restrict__ x,      // [8192, 64]
    const float* __restrict__ table,  // [64, 256]
    const float* __restrict__ scale,  // [1]
    float* __restrict__ out)          // [8192, 256]
{
    const int tid  = threadIdx.x;
    const int wave = tid >> 6;               // 0..3
    const int lane = tid & 63;               // 0..63
    const int row0 = blockIdx.x * (TD_RW * TD_W) + wave * TD_RW;

    __shared__ f4 xs[TD_W][TD_RW][TD_D / 4]; // 8 KB

    // Stage this wave's 8 rows = 128 f4 chunks; lane l takes chunk l and
    // chunk l+64 (both coalesced 1KB wave reads).
    const f4* xw = (const f4*)&x[(size_t)row0 * TD_D];
    f4 xv0 = xw[lane];
    f4 xv1 = xw[lane + 64];
    (&xs[wave][0][0])[lane]      = xv0;      // rows 0..3
    (&xs[wave][0][0])[lane + 64] = xv1;      // rows 4..7

    // X2: xv0 belongs to row (lane>>4), xv1 to row 4+(lane>>4).
    float p0 = xv0.x * xv0.x + xv0.y * xv0.y + xv0.z * xv0.z + xv0.w * xv0.w;
    float p1 = xv1.x * xv1.x + xv1.y * xv1.y + xv1.z * xv1.z + xv1.w * xv1.w;
    #pragma unroll
    for (int m = 1; m < 16; m <<= 1) {
        p0 += __shfl_xor(p0, m);
        p1 += __shfl_xor(p1, m);
    }
    float x2[TD_RW];
    #pragma unroll
    for (int r = 0; r < 4; ++r) {
        x2[r]     = __shfl(p0, r * 16);
        x2[r + 4] = __shfl(p1, r * 16);
    }

    __syncthreads();

    const f4* tb = (const f4*)table;         // [64][64] of float4 over k
    f4 acc[TD_RW];
    #pragma unroll
    for (int r = 0; r < TD_RW; ++r) acc[r] = (f4){0.f, 0.f, 0.f, 0.f};
    f4 t2 = {0.f, 0.f, 0.f, 0.f};

    #pragma unroll
    for (int dc = 0; dc < TD_D / 4; ++dc) {
        f4 t0  = tb[(dc * 4 + 0) * 64 + lane];
        f4 t1  = tb[(dc * 4 + 1) * 64 + lane];
        f4 t2v = tb[(dc * 4 + 2) * 64 + lane];
        f4 t3  = tb[(dc * 4 + 3) * 64 + lane];
        t2 += t0 * t0 + t1 * t1 + t2v * t2v + t3 * t3;
        #pragma unroll
        for (int r = 0; r < TD_RW; ++r) {
            f4 xc = xs[wave][r][dc];         // broadcast ds_read_b128
            acc[r] += t0 * xc.x + t1 * xc.y + t2v * xc.z + t3 * xc.w;
        }
    }

    const float s = fabsf(scale[0]);
    #pragma unroll
    for (int r = 0; r < TD_RW; ++r) {
        f4 res = s * (t2 + x2[r] - 2.0f * acc[r]);
        *(f4*)&out[(size_t)(row0 + r) * TD_K + lane * 4] = res;
    }
}

extern "C" void kernel_launch(void* const* d_in, const int* in_sizes, int n_in,
                              void* d_out, int out_size, void* d_ws, size_t ws_size,
                              hipStream_t stream) {
    const float* x     = (const float*)d_in[0];   // [4,2048,64]
    const float* table = (const float*)d_in[1];   // [1,1,64,256]
    const float* scale = (const float*)d_in[2];   // [1,1,1]
    float* out = (float*)d_out;                   // [4,2048,256]

    const int nrows = 4 * 2048;                           // 8192
    const int grid  = nrows / (TD_RW * TD_W);             // 256 blocks
    TableDistance_5669356831001_kernel<<<grid, 256, 0, stream>>>(x, table, scale, out);
}

// Round 5
// 12.071 us; speedup vs baseline: 1.3409x; 1.3409x over previous
//
#include <hip/hip_runtime.h>
#include <hip/hip_bf16.h>

// out[row,k] = |s| * ( T2[k] + X2[row] - 2 * dot(x_row, t_col) )
// B*N=8192 rows, D=64, K=256, fp32 in/out.
//
// R5: MFMA cross-term (bf16 16x16x32), exact-fp32 T2/X2 correction terms.
// Wave tile = 16 rows x 32 k (2 col-tiles, 4 MFMAs). 1024 blocks x 4 waves
// = 4096 waves = 4/SIMD (R1's best occupancy). Zero LDS: A-frags loaded
// from global x directly in fragment layout; B-frags gathered from the
// L2-resident 64KB table; X2/T2 via shfl reductions across lane groups.

typedef float f4 __attribute__((ext_vector_type(4)));
typedef short bf8 __attribute__((ext_vector_type(8)));   // 8 bf16 = 4 VGPR

union FragU {
    bf8 v;
    __hip_bfloat162 h[4];
};

__device__ __forceinline__ float sq4(f4 v) {
    return v.x * v.x + v.y * v.y + v.z * v.z + v.w * v.w;
}

__global__ __launch_bounds__(256)
void TableDistance_5669356831001_kernel(
    const float* __restrict__ x,      // [8192, 64]
    const float* __restrict__ table,  // [64, 256]
    const float* __restrict__ scale,  // [1]
    float* __restrict__ out)          // [8192, 256]
{
    const int tid  = threadIdx.x;
    const int wave = tid >> 6;
    const int lane = tid & 63;
    const int lr   = lane & 15;        // frag row (A) / col (B)
    const int lg   = lane >> 4;        // lane group 0..3 -> k-subrange

    const int row0  = (blockIdx.x >> 1) * 16;
    const int kbase = (blockIdx.x & 1) * 128 + wave * 32;

    // ---- A-frags: x[row0+lr][d], d = ks*32 + lg*8 + j  (j=0..7) ----
    const float* xrow = x + (size_t)(row0 + lr) * 64 + lg * 8;
    f4 xa0 = *(const f4*)(xrow +  0);   // ks=0: d = lg*8 + 0..3
    f4 xa1 = *(const f4*)(xrow +  4);   // ks=0: d = lg*8 + 4..7
    f4 xb0 = *(const f4*)(xrow + 32);   // ks=1
    f4 xb1 = *(const f4*)(xrow + 36);

    // X2[row0+lr]: own 16 squares, then sum across lane groups (xor 16,32).
    float x2p = sq4(xa0) + sq4(xa1) + sq4(xb0) + sq4(xb1);
    x2p += __shfl_xor(x2p, 16);
    x2p += __shfl_xor(x2p, 32);
    // Lane i (i<16) now holds X2[row0+i]; fetch the 4 rows this lane outputs.
    float x2v[4];
    #pragma unroll
    for (int r = 0; r < 4; ++r) x2v[r] = __shfl(x2p, lg * 4 + r);

    // Convert A to bf16 frags (v_cvt_pk_bf16_f32 via __float22bfloat162_rn).
    FragU ah0, ah1;
    ah0.h[0] = __float22bfloat162_rn(make_float2(xa0.x, xa0.y));
    ah0.h[1] = __float22bfloat162_rn(make_float2(xa0.z, xa0.w));
    ah0.h[2] = __float22bfloat162_rn(make_float2(xa1.x, xa1.y));
    ah0.h[3] = __float22bfloat162_rn(make_float2(xa1.z, xa1.w));
    ah1.h[0] = __float22bfloat162_rn(make_float2(xb0.x, xb0.y));
    ah1.h[1] = __float22bfloat162_rn(make_float2(xb0.z, xb0.w));
    ah1.h[2] = __float22bfloat162_rn(make_float2(xb1.x, xb1.y));
    ah1.h[3] = __float22bfloat162_rn(make_float2(xb1.z, xb1.w));

    // ---- B-frags + T2, 2 col-tiles; MFMA accumulate ----
    f4 acc[2];
    float t2n[2];
    #pragma unroll
    for (int nt = 0; nt < 2; ++nt) {
        const int col = kbase + nt * 16 + lr;
        const float* tp = table + (size_t)(lg * 8) * 256 + col;
        float tv[16];
        #pragma unroll
        for (int j = 0; j < 8; ++j) tv[j]     = tp[j * 256];          // ks=0
        #pragma unroll
        for (int j = 0; j < 8; ++j) tv[8 + j] = tp[(32 + j) * 256];   // ks=1

        // T2[col]: own 16 squares (disjoint d across lane groups), reduce.
        float t2p = 0.f;
        #pragma unroll
        for (int j = 0; j < 16; ++j) t2p = fmaf(tv[j], tv[j], t2p);
        t2p += __shfl_xor(t2p, 16);
        t2p += __shfl_xor(t2p, 32);
        t2n[nt] = t2p;

        FragU bh0, bh1;
        #pragma unroll
        for (int j = 0; j < 4; ++j) {
            bh0.h[j] = __float22bfloat162_rn(make_float2(tv[2 * j],     tv[2 * j + 1]));
            bh1.h[j] = __float22bfloat162_rn(make_float2(tv[8 + 2 * j], tv[8 + 2 * j + 1]));
        }

        f4 a = {0.f, 0.f, 0.f, 0.f};
        a = __builtin_amdgcn_mfma_f32_16x16x32_bf16(ah0.v, bh0.v, a, 0, 0, 0);
        a = __builtin_amdgcn_mfma_f32_16x16x32_bf16(ah1.v, bh1.v, a, 0, 0, 0);
        acc[nt] = a;
    }

    // ---- Epilogue: C/D layout col=lane&15, row=(lane>>4)*4+reg ----
    const float s = fabsf(scale[0]);
    #pragma unroll
    for (int nt = 0; nt < 2; ++nt) {
        const int col = kbase + nt * 16 + lr;
        #pragma unroll
        for (int r = 0; r < 4; ++r) {
            const int row = row0 + lg * 4 + r;
            out[(size_t)row * 256 + col] = s * (t2n[nt] + x2v[r] - 2.0f * acc[nt][r]);
        }
    }
}

extern "C" void kernel_launch(void* const* d_in, const int* in_sizes, int n_in,
                              void* d_out, int out_size, void* d_ws, size_t ws_size,
                              hipStream_t stream) {
    const float* x     = (const float*)d_in[0];   // [4,2048,64]
    const float* table = (const float*)d_in[1];   // [1,1,64,256]
    const float* scale = (const float*)d_in[2];   // [1,1,1]
    float* out = (float*)d_out;                   // [4,2048,256]

    // 512 row-blocks x 2 k-halves = 1024 blocks of 256 threads (4 waves).
    TableDistance_5669356831001_kernel<<<1024, 256, 0, stream>>>(x, table, scale, out);
}